// Round 12
// baseline (99.268 us; speedup 1.0000x reference)
//
#include <hip/hip_runtime.h>

// DFMBPSROIAlign. R12: branchless footprint, done correctly.
//  R11 bug: clamping xbase/ybase shifted the read window under weights
//  indexed relative to the ORIGINAL base -> wrong pixels for edge ROIs.
//  R12: keep the original base (all nonzero-weight indices are in-bounds
//  since x1/x2,y1/y2 are clamped to <=33); make the zero-weight overreads
//  DEFINED by padding the slab with 3 rows + 4 px of zeros (0*0 = exact 0).
//  Slab 1264 px * 32B = 40448B; 4 blocks/CU * 40448 = 161792 <= 163840 LDS.
//  Math identical to passing R10 + exact-zero additions -> absmax 0.03125.

constexpr int C  = 10;
constexpr int PH = 7;
constexpr int PW = 7;
constexpr int H  = 34;
constexpr int W  = 34;
constexpr int P  = PH * PW;         // 49
constexpr int HW = H * W;           // 1156
constexpr int FT_C_STRIDE = P * HW; // 56644
constexpr int SPX = 16;             // ushorts per pixel (10 ch + 6 pad), 32B
constexpr int SLAB_PIX = 1264;      // >= (H+2)*W + (W+2) + 1 = 1261, mult of 8
constexpr int SLAB_US  = SLAB_PIX * SPX;   // 20224 us = 40448 B
constexpr int DATA_US  = HW * SPX;         // 18496 us (real pixels)
constexpr int CPAD = 12;            // fp32 fallback floats/pixel
constexpr int FB_PIX = 1264;        // fallback padded pixels
constexpr int R  = C * P;           // 490
constexpr int RU = (C / 2) * P;     // 245 uint rows (bf16 channel pairs)

typedef float vf2 __attribute__((ext_vector_type(2)));  // native vec for NT store

__device__ inline unsigned bf16rn(float f) {
    unsigned u = __float_as_uint(f);
    return (u + 0x7FFFu + ((u >> 16) & 1u)) >> 16;
}
__device__ inline float bf16lo(unsigned u) { return __uint_as_float(u << 16); }
__device__ inline float bf16hi(unsigned u) { return __uint_as_float(u & 0xFFFF0000u); }

// ---- pack ft (C,P,H,W) fp32 -> ftB[p][pix][16 bf16]; grid (49,5) ----
__global__ __launch_bounds__(256) void dfmb_pack(
    const float* __restrict__ ft, ushort* __restrict__ ftB)
{
    const int p   = blockIdx.x;
    const int pix = blockIdx.y * 256 + threadIdx.x;
    if (pix >= HW) return;
    const float* __restrict__ src = ft + p * HW;
    unsigned d[8];
#pragma unroll
    for (int k = 0; k < 5; ++k) {
        float a = src[(2 * k) * FT_C_STRIDE + pix];
        float b = src[(2 * k + 1) * FT_C_STRIDE + pix];
        d[k] = bf16rn(a) | (bf16rn(b) << 16);
    }
    d[5] = 0; d[6] = 0; d[7] = 0;
    uint4* dst = (uint4*)(ftB + (size_t)p * DATA_US + pix * SPX);
    dst[0] = make_uint4(d[0], d[1], d[2], d[3]);
    dst[1] = make_uint4(d[4], d[5], d[6], d[7]);
}

// ---- main: bf16 LDS slab gather, branchless 4x4 footprint ----
__global__ __launch_bounds__(512) void dfmb_main(
    const ushort* __restrict__ ftB,
    const float* __restrict__ rois,
    unsigned* __restrict__ ws,  // [n/64][c2*49+p][n%64] bf16 pairs
    int N)
{
    __shared__ ushort slab[SLAB_US];    // 40448 B (incl. zero pad rows)

    const int p  = blockIdx.y;
    const int ph = p / PW;
    const int pw = p - ph * PW;

    // Dense conflict-free staging (2312 uint4) + zero the pad (216 uint4).
    {
        const uint4* __restrict__ s4 = (const uint4*)(ftB + (size_t)p * DATA_US);
        uint4* d4 = (uint4*)slab;
        for (int i = threadIdx.x; i < DATA_US / 8; i += 512) d4[i] = s4[i];
        const uint4 z = make_uint4(0, 0, 0, 0);
        for (int i = DATA_US / 8 + threadIdx.x; i < SLAB_US / 8; i += 512) d4[i] = z;
    }
    __syncthreads();

    const int n = blockIdx.x * 512 + threadIdx.x;
    if (n >= N) return;

    // Coordinate setup — contraction OFF so floor() args match the reference
    // rounding (verified passing R0-R10).
    float wstart, hstart, sub_w, sub_h;
    {
#pragma clang fp contract(off)
        const float inv_stride = 0.0625f;
        float rsw = rois[n * 5 + 1] * inv_stride;
        float rsh = rois[n * 5 + 2] * inv_stride;
        float rew = rois[n * 5 + 3] * inv_stride;
        float reh = rois[n * 5 + 4] * inv_stride;
        float roi_h = reh - rsh; if (!(roi_h > 0.1f)) roi_h = 0.1f;
        float roi_w = rew - rsw; if (!(roi_w > 0.1f)) roi_w = 0.1f;
        float bin_h = roi_h / 7.0f;
        float bin_w = roi_w / 7.0f;
        sub_h = bin_h * 0.25f;
        sub_w = bin_w * 0.25f;
        hstart = floorf(rsh + (float)ph * bin_h);
        wstart = floorf(rsw + (float)pw * bin_w);
    }

    // ---- separable 1-D weight footprints (<=4 cols x <=4 rows) ----
    float Xw0 = 0.f, Xw1 = 0.f, Xw2 = 0.f, Xw3 = 0.f, cntx = 0.f;
    int xbase = 0;
#pragma unroll
    for (int iw = 0; iw < 4; ++iw) {
        float w;
        {
#pragma clang fp contract(off)
            w = wstart + ((float)iw + 0.5f) * sub_w;
        }
        float kw  = (w > -1.0f && w < 34.0f) ? 1.0f : 0.0f;
        float x1f = floorf(w), x2f = ceilf(w);
        float x1v = (x1f >= 0.0f && x1f < 34.0f) ? 1.0f : 0.0f;
        float x2v = (x2f >= 0.0f && x2f < 34.0f) ? 1.0f : 0.0f;
        int x1 = (int)fminf(fmaxf(x1f, 0.0f), 33.0f);
        int x2 = (int)fminf(fmaxf(x2f, 0.0f), 33.0f);
        float dx = w - (float)x1;           // vs CLAMPED corner (ref semantics)
        if (iw == 0) xbase = x1;            // minimal column (w monotone in iw)
        float a = kw * (1.0f - dx) * x1v;
        float b = kw * dx * x2v;
        int i1 = x1 - xbase, i2 = x2 - xbase;
        Xw0 += (i1 == 0) ? a : 0.f;  Xw1 += (i1 == 1) ? a : 0.f;
        Xw2 += (i1 == 2) ? a : 0.f;  Xw3 += (i1 == 3) ? a : 0.f;
        Xw0 += (i2 == 0) ? b : 0.f;  Xw1 += (i2 == 1) ? b : 0.f;
        Xw2 += (i2 == 2) ? b : 0.f;  Xw3 += (i2 == 3) ? b : 0.f;
        cntx += kw;
    }

    float Yw0 = 0.f, Yw1 = 0.f, Yw2 = 0.f, Yw3 = 0.f, cnty = 0.f;
    int ybase = 0;
#pragma unroll
    for (int ih = 0; ih < 4; ++ih) {
        float h;
        {
#pragma clang fp contract(off)
            h = hstart + ((float)ih + 0.5f) * sub_h;
        }
        float kh  = (h > -1.0f && h < 34.0f) ? 1.0f : 0.0f;
        float y1f = floorf(h), y2f = ceilf(h);
        float y1v = (y1f >= 0.0f && y1f < 34.0f) ? 1.0f : 0.0f;
        float y2v = (y2f >= 0.0f && y2f < 34.0f) ? 1.0f : 0.0f;
        int y1 = (int)fminf(fmaxf(y1f, 0.0f), 33.0f);
        int y2 = (int)fminf(fmaxf(y2f, 0.0f), 33.0f);
        float dy = h - (float)y1;
        if (ih == 0) ybase = y1;
        float a = kh * (1.0f - dy) * y1v;
        float b = kh * dy * y2v;
        int i1 = y1 - ybase, i2 = y2 - ybase;
        Yw0 += (i1 == 0) ? a : 0.f;  Yw1 += (i1 == 1) ? a : 0.f;
        Yw2 += (i1 == 2) ? a : 0.f;  Yw3 += (i1 == 3) ? a : 0.f;
        Yw0 += (i2 == 0) ? b : 0.f;  Yw1 += (i2 == 1) ? b : 0.f;
        Yw2 += (i2 == 2) ? b : 0.f;  Yw3 += (i2 == 3) ? b : 0.f;
        cnty += kh;
    }

    // ---- branchless accumulate: 16 unconditional pixel reads.
    // Nonzero-weight indices are always in the real slab (x1/x2,y1/y2
    // clamped <= 33); zero-weight slots may land in the zero pad: +0 exact.
    const float Xw[4] = {Xw0, Xw1, Xw2, Xw3};
    const float Yw[4] = {Yw0, Yw1, Yw2, Yw3};
    float s0=0.f,s1=0.f,s2=0.f,s3=0.f,s4=0.f,s5=0.f,s6=0.f,s7=0.f,s8=0.f,s9=0.f;
    const ushort* base = slab + (ybase * W + xbase) * SPX;
#pragma unroll
    for (int cy = 0; cy < 4; ++cy) {
        const ushort* rowp = base + cy * (W * SPX);
#pragma unroll
        for (int cx = 0; cx < 4; ++cx) {
            float wgt = Yw[cy] * Xw[cx];
            const ushort* t = rowp + cx * SPX;
            uint4 a = *(const uint4*)(t);       // ch 0..7
            uint2 b = *(const uint2*)(t + 8);   // ch 8..9 (+pad)
            s0 += wgt * bf16lo(a.x);  s1 += wgt * bf16hi(a.x);
            s2 += wgt * bf16lo(a.y);  s3 += wgt * bf16hi(a.y);
            s4 += wgt * bf16lo(a.z);  s5 += wgt * bf16hi(a.z);
            s6 += wgt * bf16lo(a.w);  s7 += wgt * bf16hi(a.w);
            s8 += wgt * bf16lo(b.x);  s9 += wgt * bf16hi(b.x);
        }
    }

    float cnt = cntx * cnty;
    if (!(cnt > 0.0f)) cnt = 1.0f;
    float inv = 1.0f / cnt;

    // Pack 10 results into 5 bf16-pair uints; blocked coalesced stores.
    unsigned r01 = bf16rn(s0 * inv) | (bf16rn(s1 * inv) << 16);
    unsigned r23 = bf16rn(s2 * inv) | (bf16rn(s3 * inv) << 16);
    unsigned r45 = bf16rn(s4 * inv) | (bf16rn(s5 * inv) << 16);
    unsigned r67 = bf16rn(s6 * inv) | (bf16rn(s7 * inv) << 16);
    unsigned r89 = bf16rn(s8 * inv) | (bf16rn(s9 * inv) << 16);

    unsigned* __restrict__ o = ws + (size_t)(n >> 6) * (RU * 64)
                                  + (size_t)p * 64 + (n & 63);
    o[0 * (P * 64)] = r01;
    o[1 * (P * 64)] = r23;
    o[2 * (P * 64)] = r45;
    o[3 * (P * 64)] = r67;
    o[4 * (P * 64)] = r89;
}

// Per-64n-slab transpose+unpack: ws[nblk][c2*49+p][nl] (245x64 uints,
// contiguous 62.7KB) -> out[n][c*49+p] fp32, nontemporal vf2 stores.
__global__ __launch_bounds__(1024) void dfmb_phase2(
    const unsigned* __restrict__ ws, float* __restrict__ out, int N)
{
    __shared__ unsigned t[RU * 65];     // 63700 B
    const int nblk = blockIdx.x;
    const unsigned* __restrict__ srcb = ws + (size_t)nblk * (RU * 64);

    // Load 245 rows x 64 nl contiguous via uint4 (3920 of them).
    for (int i = threadIdx.x; i < RU * 16; i += 1024) {
        int rr  = i >> 4;
        int nl4 = (i & 15) * 4;
        uint4 v = ((const uint4*)srcb)[i];
        unsigned* tp = &t[rr * 65 + nl4];
        tp[0] = v.x; tp[1] = v.y; tp[2] = v.z; tp[3] = v.w;
    }
    __syncthreads();

    // Write out[n0+nl][2k..2k+1]: lane-consecutive k -> coalesced 512B vf2.
    const int n0 = nblk * 64;
    for (int j = threadIdx.x; j < 64 * (R / 2); j += 1024) {
        int nl = j / (R / 2);
        int k  = j - nl * (R / 2);
        int r0 = 2 * k, r1 = 2 * k + 1;
        int c0 = r0 / P, p0 = r0 - c0 * P;
        int c1 = r1 / P, p1 = r1 - c1 * P;
        unsigned u0 = t[((c0 >> 1) * P + p0) * 65 + nl];
        unsigned u1 = t[((c1 >> 1) * P + p1) * 65 + nl];
        vf2 v;
        v.x = (c0 & 1) ? bf16hi(u0) : bf16lo(u0);
        v.y = (c1 & 1) ? bf16hi(u1) : bf16lo(u1);
        __builtin_nontemporal_store(v, (vf2*)(out + (size_t)(n0 + nl) * R) + k);
    }
}

// ---- fallback (no ws): fp32 LDS-slab kernel, branchless w/ zero pad ----
__global__ __launch_bounds__(512, 4) void dfmb_phase1_direct(
    const float* __restrict__ ft,
    const float* __restrict__ rois,
    float* __restrict__ dst,
    int N)
{
    __shared__ float tile[FB_PIX * CPAD];   // 60672 B (incl. zero pad)
    const int p  = blockIdx.y;
    const int ph = p / PW;
    const int pw = p - ph * PW;
    const float* __restrict__ src = ft + p * HW;
    for (int i = threadIdx.x; i < C * HW; i += 512) {
        int c = i / HW;
        int r = i - c * HW;
        tile[r * CPAD + c] = src[c * FT_C_STRIDE + r];
    }
    for (int i = HW * CPAD + threadIdx.x; i < FB_PIX * CPAD; i += 512)
        tile[i] = 0.0f;
    __syncthreads();
    const int n = blockIdx.x * 512 + threadIdx.x;
    if (n >= N) return;
    float wstart, hstart, sub_w, sub_h;
    {
#pragma clang fp contract(off)
        const float inv_stride = 0.0625f;
        float rsw = rois[n * 5 + 1] * inv_stride;
        float rsh = rois[n * 5 + 2] * inv_stride;
        float rew = rois[n * 5 + 3] * inv_stride;
        float reh = rois[n * 5 + 4] * inv_stride;
        float roi_h = reh - rsh; if (!(roi_h > 0.1f)) roi_h = 0.1f;
        float roi_w = rew - rsw; if (!(roi_w > 0.1f)) roi_w = 0.1f;
        float bin_h = roi_h / 7.0f;
        float bin_w = roi_w / 7.0f;
        sub_h = bin_h * 0.25f;
        sub_w = bin_w * 0.25f;
        hstart = floorf(rsh + (float)ph * bin_h);
        wstart = floorf(rsw + (float)pw * bin_w);
    }
    float Xw0=0.f,Xw1=0.f,Xw2=0.f,Xw3=0.f,cntx=0.f;
    float Yw0=0.f,Yw1=0.f,Yw2=0.f,Yw3=0.f,cnty=0.f;
    int xbase = 0, ybase = 0;
#pragma unroll
    for (int iw = 0; iw < 4; ++iw) {
        float w;
        {
#pragma clang fp contract(off)
            w = wstart + ((float)iw + 0.5f) * sub_w;
        }
        float kw  = (w > -1.0f && w < 34.0f) ? 1.0f : 0.0f;
        float x1f = floorf(w), x2f = ceilf(w);
        float x1v = (x1f >= 0.0f && x1f < 34.0f) ? 1.0f : 0.0f;
        float x2v = (x2f >= 0.0f && x2f < 34.0f) ? 1.0f : 0.0f;
        int x1 = (int)fminf(fmaxf(x1f, 0.0f), 33.0f);
        int x2 = (int)fminf(fmaxf(x2f, 0.0f), 33.0f);
        float dx = w - (float)x1;
        if (iw == 0) xbase = x1;
        float a = kw * (1.0f - dx) * x1v;
        float b = kw * dx * x2v;
        int i1 = x1 - xbase, i2 = x2 - xbase;
        Xw0 += (i1==0)?a:0.f; Xw1 += (i1==1)?a:0.f; Xw2 += (i1==2)?a:0.f; Xw3 += (i1==3)?a:0.f;
        Xw0 += (i2==0)?b:0.f; Xw1 += (i2==1)?b:0.f; Xw2 += (i2==2)?b:0.f; Xw3 += (i2==3)?b:0.f;
        cntx += kw;
    }
#pragma unroll
    for (int ih = 0; ih < 4; ++ih) {
        float h;
        {
#pragma clang fp contract(off)
            h = hstart + ((float)ih + 0.5f) * sub_h;
        }
        float kh  = (h > -1.0f && h < 34.0f) ? 1.0f : 0.0f;
        float y1f = floorf(h), y2f = ceilf(h);
        float y1v = (y1f >= 0.0f && y1f < 34.0f) ? 1.0f : 0.0f;
        float y2v = (y2f >= 0.0f && y2f < 34.0f) ? 1.0f : 0.0f;
        int y1 = (int)fminf(fmaxf(y1f, 0.0f), 33.0f);
        int y2 = (int)fminf(fmaxf(y2f, 0.0f), 33.0f);
        float dy = h - (float)y1;
        if (ih == 0) ybase = y1;
        float a = kh * (1.0f - dy) * y1v;
        float b = kh * dy * y2v;
        int i1 = y1 - ybase, i2 = y2 - ybase;
        Yw0 += (i1==0)?a:0.f; Yw1 += (i1==1)?a:0.f; Yw2 += (i1==2)?a:0.f; Yw3 += (i1==3)?a:0.f;
        Yw0 += (i2==0)?b:0.f; Yw1 += (i2==1)?b:0.f; Yw2 += (i2==2)?b:0.f; Yw3 += (i2==3)?b:0.f;
        cnty += kh;
    }
    const float Xw[4] = {Xw0, Xw1, Xw2, Xw3};
    const float Yw[4] = {Yw0, Yw1, Yw2, Yw3};
    float4 v0s = {0,0,0,0}, v1s = {0,0,0,0};
    float2 v2s = {0,0};
    const float* basep = &tile[(ybase * W + xbase) * CPAD];
#pragma unroll
    for (int cy = 0; cy < 4; ++cy) {
        const float* rowp = basep + cy * (W * CPAD);
#pragma unroll
        for (int cx = 0; cx < 4; ++cx) {
            float wgt = Yw[cy] * Xw[cx];
            const float* t = rowp + cx * CPAD;
            float4 a = *(const float4*)(t);
            float4 b = *(const float4*)(t + 4);
            float2 c2 = *(const float2*)(t + 8);
            v0s.x += wgt*a.x; v0s.y += wgt*a.y; v0s.z += wgt*a.z; v0s.w += wgt*a.w;
            v1s.x += wgt*b.x; v1s.y += wgt*b.y; v1s.z += wgt*b.z; v1s.w += wgt*b.w;
            v2s.x += wgt*c2.x; v2s.y += wgt*c2.y;
        }
    }
    float cnt = cntx * cnty;
    if (!(cnt > 0.0f)) cnt = 1.0f;
    float inv = 1.0f / cnt;
    float r[10] = { v0s.x*inv, v0s.y*inv, v0s.z*inv, v0s.w*inv,
                    v1s.x*inv, v1s.y*inv, v1s.z*inv, v1s.w*inv,
                    v2s.x*inv, v2s.y*inv };
    float* __restrict__ o = dst + (size_t)n * R + p;
#pragma unroll
    for (int c = 0; c < C; ++c) o[c * P] = r[c];
}

extern "C" void kernel_launch(void* const* d_in, const int* in_sizes, int n_in,
                              void* d_out, int out_size, void* d_ws, size_t ws_size,
                              hipStream_t stream) {
    const float* ft   = (const float*)d_in[0];
    const float* rois = (const float*)d_in[1];
    float* out = (float*)d_out;
    const int N = in_sizes[1] / 5;

    const size_t packB = (size_t)P * DATA_US * sizeof(ushort); // 1.81 MB
    const size_t wsOff = (packB + 255) & ~(size_t)255;
    const size_t need  = wsOff + (size_t)RU * N * sizeof(unsigned); // +16 MB
    if (d_ws != nullptr && ws_size >= need && (N % 64) == 0) {
        ushort*   ftB = (ushort*)d_ws;
        unsigned* ws2 = (unsigned*)((char*)d_ws + wsOff);
        dfmb_pack<<<dim3(P, (HW + 255) / 256), dim3(256), 0, stream>>>(ft, ftB);
        dfmb_main<<<dim3((N + 511) / 512, P), dim3(512), 0, stream>>>(ftB, rois, ws2, N);
        dfmb_phase2<<<dim3(N / 64), dim3(1024), 0, stream>>>(ws2, out, N);
    } else {
        dim3 grid1((N + 511) / 512, P);
        dfmb_phase1_direct<<<grid1, dim3(512), 0, stream>>>(ft, rois, out, N);
    }
}

// Round 13
// 95.757 us; speedup vs baseline: 1.0367x; 1.0367x over previous
//
#include <hip/hip_runtime.h>

// DFMBPSROIAlign. R13 = exact revert to R10 (best measured: 95.3us).
//  R12 post-mortem: branchless footprint REGRESSED (99.3us) — divergent
//  per-pixel skips save real work (typical live footprint is 6-9 of 16
//  pixels); unconditional reads + pad-zeroing + 40KB slab cost more than
//  the exec-mask churn they removed. R10 config is the plateau:
//  - pack ft->bf16 [p][pix][16] (grid 49x5)
//  - main: 512-thr blocks, 37KB bf16 LDS slab, separable <=4x<=4 weights,
//    conditional pixel reads (b128+b64), bf16-pair blocked ws stores
//  - phase2: 64n-slab transpose+unpack, nontemporal vf2 stores
//  Timed-window floor: ~46us 256MiB ws poison + ~6us out poison + restores;
//  kernels ~35us. No remaining single lever >2us identified (R7-R12 probes).

constexpr int C  = 10;
constexpr int PH = 7;
constexpr int PW = 7;
constexpr int H  = 34;
constexpr int W  = 34;
constexpr int P  = PH * PW;         // 49
constexpr int HW = H * W;           // 1156
constexpr int FT_C_STRIDE = P * HW; // 56644
constexpr int SPX = 16;             // ushorts per pixel (10 ch + 6 pad), 32B
constexpr int SLAB_US = HW * SPX;   // 18496 ushorts = 36992 B
constexpr int CPAD = 12;            // fp32 fallback pad
constexpr int R  = C * P;           // 490
constexpr int RU = (C / 2) * P;     // 245 uint rows (bf16 channel pairs)

typedef float vf2 __attribute__((ext_vector_type(2)));  // native vec for NT store

__device__ inline unsigned bf16rn(float f) {
    unsigned u = __float_as_uint(f);
    return (u + 0x7FFFu + ((u >> 16) & 1u)) >> 16;
}
__device__ inline float bf16lo(unsigned u) { return __uint_as_float(u << 16); }
__device__ inline float bf16hi(unsigned u) { return __uint_as_float(u & 0xFFFF0000u); }

// ---- pack ft (C,P,H,W) fp32 -> ftB[p][pix][16 bf16]; grid (49,5) ----
__global__ __launch_bounds__(256) void dfmb_pack(
    const float* __restrict__ ft, ushort* __restrict__ ftB)
{
    const int p   = blockIdx.x;
    const int pix = blockIdx.y * 256 + threadIdx.x;
    if (pix >= HW) return;
    const float* __restrict__ src = ft + p * HW;
    unsigned d[8];
#pragma unroll
    for (int k = 0; k < 5; ++k) {
        float a = src[(2 * k) * FT_C_STRIDE + pix];
        float b = src[(2 * k + 1) * FT_C_STRIDE + pix];
        d[k] = bf16rn(a) | (bf16rn(b) << 16);
    }
    d[5] = 0; d[6] = 0; d[7] = 0;
    uint4* dst = (uint4*)(ftB + (size_t)p * SLAB_US + pix * SPX);
    dst[0] = make_uint4(d[0], d[1], d[2], d[3]);
    dst[1] = make_uint4(d[4], d[5], d[6], d[7]);
}

// ---- main: bf16 LDS slab gather, bf16-pair packed blocked ws out ----
__global__ __launch_bounds__(512) void dfmb_main(
    const ushort* __restrict__ ftB,
    const float* __restrict__ rois,
    unsigned* __restrict__ ws,  // [n/64][c2*49+p][n%64] bf16 pairs
    int N)
{
    __shared__ ushort slab[SLAB_US];    // 36992 B

    const int p  = blockIdx.y;
    const int ph = p / PW;
    const int pw = p - ph * PW;

    // Dense conflict-free staging: 2312 uint4 over 512 threads.
    {
        const uint4* __restrict__ s4 = (const uint4*)(ftB + (size_t)p * SLAB_US);
        uint4* d4 = (uint4*)slab;
        for (int i = threadIdx.x; i < SLAB_US / 8; i += 512) d4[i] = s4[i];
    }
    __syncthreads();

    const int n = blockIdx.x * 512 + threadIdx.x;
    if (n >= N) return;

    // Coordinate setup — contraction OFF so floor() args match the reference
    // rounding (verified passing R0-R10).
    float wstart, hstart, sub_w, sub_h;
    {
#pragma clang fp contract(off)
        const float inv_stride = 0.0625f;
        float rsw = rois[n * 5 + 1] * inv_stride;
        float rsh = rois[n * 5 + 2] * inv_stride;
        float rew = rois[n * 5 + 3] * inv_stride;
        float reh = rois[n * 5 + 4] * inv_stride;
        float roi_h = reh - rsh; if (!(roi_h > 0.1f)) roi_h = 0.1f;
        float roi_w = rew - rsw; if (!(roi_w > 0.1f)) roi_w = 0.1f;
        float bin_h = roi_h / 7.0f;
        float bin_w = roi_w / 7.0f;
        sub_h = bin_h * 0.25f;
        sub_w = bin_w * 0.25f;
        hstart = floorf(rsh + (float)ph * bin_h);
        wstart = floorf(rsw + (float)pw * bin_w);
    }

    // ---- separable 1-D weight footprints (<=4 cols x <=4 rows) ----
    float Xw0 = 0.f, Xw1 = 0.f, Xw2 = 0.f, Xw3 = 0.f, cntx = 0.f;
    int xbase = 0;
#pragma unroll
    for (int iw = 0; iw < 4; ++iw) {
        float w;
        {
#pragma clang fp contract(off)
            w = wstart + ((float)iw + 0.5f) * sub_w;
        }
        float kw  = (w > -1.0f && w < 34.0f) ? 1.0f : 0.0f;
        float x1f = floorf(w), x2f = ceilf(w);
        float x1v = (x1f >= 0.0f && x1f < 34.0f) ? 1.0f : 0.0f;
        float x2v = (x2f >= 0.0f && x2f < 34.0f) ? 1.0f : 0.0f;
        int x1 = (int)fminf(fmaxf(x1f, 0.0f), 33.0f);
        int x2 = (int)fminf(fmaxf(x2f, 0.0f), 33.0f);
        float dx = w - (float)x1;           // vs CLAMPED corner (ref semantics)
        if (iw == 0) xbase = x1;            // minimal column (w monotone in iw)
        float a = kw * (1.0f - dx) * x1v;
        float b = kw * dx * x2v;
        int i1 = x1 - xbase, i2 = x2 - xbase;
        Xw0 += (i1 == 0) ? a : 0.f;  Xw1 += (i1 == 1) ? a : 0.f;
        Xw2 += (i1 == 2) ? a : 0.f;  Xw3 += (i1 == 3) ? a : 0.f;
        Xw0 += (i2 == 0) ? b : 0.f;  Xw1 += (i2 == 1) ? b : 0.f;
        Xw2 += (i2 == 2) ? b : 0.f;  Xw3 += (i2 == 3) ? b : 0.f;
        cntx += kw;
    }

    float Yw0 = 0.f, Yw1 = 0.f, Yw2 = 0.f, Yw3 = 0.f, cnty = 0.f;
    int ybase = 0;
#pragma unroll
    for (int ih = 0; ih < 4; ++ih) {
        float h;
        {
#pragma clang fp contract(off)
            h = hstart + ((float)ih + 0.5f) * sub_h;
        }
        float kh  = (h > -1.0f && h < 34.0f) ? 1.0f : 0.0f;
        float y1f = floorf(h), y2f = ceilf(h);
        float y1v = (y1f >= 0.0f && y1f < 34.0f) ? 1.0f : 0.0f;
        float y2v = (y2f >= 0.0f && y2f < 34.0f) ? 1.0f : 0.0f;
        int y1 = (int)fminf(fmaxf(y1f, 0.0f), 33.0f);
        int y2 = (int)fminf(fmaxf(y2f, 0.0f), 33.0f);
        float dy = h - (float)y1;
        if (ih == 0) ybase = y1;
        float a = kh * (1.0f - dy) * y1v;
        float b = kh * dy * y2v;
        int i1 = y1 - ybase, i2 = y2 - ybase;
        Yw0 += (i1 == 0) ? a : 0.f;  Yw1 += (i1 == 1) ? a : 0.f;
        Yw2 += (i1 == 2) ? a : 0.f;  Yw3 += (i1 == 3) ? a : 0.f;
        Yw0 += (i2 == 0) ? b : 0.f;  Yw1 += (i2 == 1) ? b : 0.f;
        Yw2 += (i2 == 2) ? b : 0.f;  Yw3 += (i2 == 3) ? b : 0.f;
        cnty += kh;
    }

    // ---- accumulate over footprint: b128 + b64 per pixel (10 bf16 ch) ----
    float s0=0.f,s1=0.f,s2=0.f,s3=0.f,s4=0.f,s5=0.f,s6=0.f,s7=0.f,s8=0.f,s9=0.f;
#pragma unroll
    for (int cy = 0; cy < 4; ++cy) {
        float wy = (cy == 0) ? Yw0 : (cy == 1) ? Yw1 : (cy == 2) ? Yw2 : Yw3;
        if (wy != 0.0f) {
            int yy = min(ybase + cy, 33);
            const ushort* rowp = slab + yy * (W * SPX);
#pragma unroll
            for (int cx = 0; cx < 4; ++cx) {
                float wx = (cx == 0) ? Xw0 : (cx == 1) ? Xw1
                         : (cx == 2) ? Xw2 : Xw3;
                float wgt = wy * wx;
                if (wgt != 0.0f) {
                    int xx = min(xbase + cx, 33);
                    const ushort* t = rowp + xx * SPX;
                    uint4 a = *(const uint4*)(t);       // ch 0..7
                    uint2 b = *(const uint2*)(t + 8);   // ch 8..9 (+pad)
                    s0 += wgt * bf16lo(a.x);  s1 += wgt * bf16hi(a.x);
                    s2 += wgt * bf16lo(a.y);  s3 += wgt * bf16hi(a.y);
                    s4 += wgt * bf16lo(a.z);  s5 += wgt * bf16hi(a.z);
                    s6 += wgt * bf16lo(a.w);  s7 += wgt * bf16hi(a.w);
                    s8 += wgt * bf16lo(b.x);  s9 += wgt * bf16hi(b.x);
                }
            }
        }
    }

    float cnt = cntx * cnty;
    if (!(cnt > 0.0f)) cnt = 1.0f;
    float inv = 1.0f / cnt;

    // Pack 10 results into 5 bf16-pair uints; blocked coalesced stores.
    unsigned r01 = bf16rn(s0 * inv) | (bf16rn(s1 * inv) << 16);
    unsigned r23 = bf16rn(s2 * inv) | (bf16rn(s3 * inv) << 16);
    unsigned r45 = bf16rn(s4 * inv) | (bf16rn(s5 * inv) << 16);
    unsigned r67 = bf16rn(s6 * inv) | (bf16rn(s7 * inv) << 16);
    unsigned r89 = bf16rn(s8 * inv) | (bf16rn(s9 * inv) << 16);

    unsigned* __restrict__ o = ws + (size_t)(n >> 6) * (RU * 64)
                                  + (size_t)p * 64 + (n & 63);
    o[0 * (P * 64)] = r01;
    o[1 * (P * 64)] = r23;
    o[2 * (P * 64)] = r45;
    o[3 * (P * 64)] = r67;
    o[4 * (P * 64)] = r89;
}

// Per-64n-slab transpose+unpack: ws[nblk][c2*49+p][nl] (245x64 uints,
// contiguous 62.7KB) -> out[n][c*49+p] fp32, nontemporal vf2 stores.
__global__ __launch_bounds__(1024) void dfmb_phase2(
    const unsigned* __restrict__ ws, float* __restrict__ out, int N)
{
    __shared__ unsigned t[RU * 65];     // 63700 B
    const int nblk = blockIdx.x;
    const unsigned* __restrict__ srcb = ws + (size_t)nblk * (RU * 64);

    // Load 245 rows x 64 nl contiguous via uint4 (3920 of them).
    for (int i = threadIdx.x; i < RU * 16; i += 1024) {
        int rr  = i >> 4;
        int nl4 = (i & 15) * 4;
        uint4 v = ((const uint4*)srcb)[i];
        unsigned* tp = &t[rr * 65 + nl4];
        tp[0] = v.x; tp[1] = v.y; tp[2] = v.z; tp[3] = v.w;
    }
    __syncthreads();

    // Write out[n0+nl][2k..2k+1]: lane-consecutive k -> coalesced 512B vf2.
    const int n0 = nblk * 64;
    for (int j = threadIdx.x; j < 64 * (R / 2); j += 1024) {
        int nl = j / (R / 2);
        int k  = j - nl * (R / 2);
        int r0 = 2 * k, r1 = 2 * k + 1;
        int c0 = r0 / P, p0 = r0 - c0 * P;
        int c1 = r1 / P, p1 = r1 - c1 * P;
        unsigned u0 = t[((c0 >> 1) * P + p0) * 65 + nl];
        unsigned u1 = t[((c1 >> 1) * P + p1) * 65 + nl];
        vf2 v;
        v.x = (c0 & 1) ? bf16hi(u0) : bf16lo(u0);
        v.y = (c1 & 1) ? bf16hi(u1) : bf16lo(u1);
        __builtin_nontemporal_store(v, (vf2*)(out + (size_t)(n0 + nl) * R) + k);
    }
}

// ---- fallback (no ws): fp32 LDS-slab kernel, direct strided writes ----
__global__ __launch_bounds__(512, 4) void dfmb_phase1_direct(
    const float* __restrict__ ft,
    const float* __restrict__ rois,
    float* __restrict__ dst,
    int N)
{
    __shared__ float tile[HW * CPAD];
    const int p  = blockIdx.y;
    const int ph = p / PW;
    const int pw = p - ph * PW;
    const float* __restrict__ src = ft + p * HW;
    for (int i = threadIdx.x; i < C * HW; i += 512) {
        int c = i / HW;
        int r = i - c * HW;
        tile[r * CPAD + c] = src[c * FT_C_STRIDE + r];
    }
    __syncthreads();
    const int n = blockIdx.x * 512 + threadIdx.x;
    if (n >= N) return;
    float wstart, hstart, sub_w, sub_h;
    {
#pragma clang fp contract(off)
        const float inv_stride = 0.0625f;
        float rsw = rois[n * 5 + 1] * inv_stride;
        float rsh = rois[n * 5 + 2] * inv_stride;
        float rew = rois[n * 5 + 3] * inv_stride;
        float reh = rois[n * 5 + 4] * inv_stride;
        float roi_h = reh - rsh; if (!(roi_h > 0.1f)) roi_h = 0.1f;
        float roi_w = rew - rsw; if (!(roi_w > 0.1f)) roi_w = 0.1f;
        float bin_h = roi_h / 7.0f;
        float bin_w = roi_w / 7.0f;
        sub_h = bin_h * 0.25f;
        sub_w = bin_w * 0.25f;
        hstart = floorf(rsh + (float)ph * bin_h);
        wstart = floorf(rsw + (float)pw * bin_w);
    }
    float Xw0=0.f,Xw1=0.f,Xw2=0.f,Xw3=0.f,cntx=0.f;
    float Yw0=0.f,Yw1=0.f,Yw2=0.f,Yw3=0.f,cnty=0.f;
    int xbase = 0, ybase = 0;
#pragma unroll
    for (int iw = 0; iw < 4; ++iw) {
        float w;
        {
#pragma clang fp contract(off)
            w = wstart + ((float)iw + 0.5f) * sub_w;
        }
        float kw  = (w > -1.0f && w < 34.0f) ? 1.0f : 0.0f;
        float x1f = floorf(w), x2f = ceilf(w);
        float x1v = (x1f >= 0.0f && x1f < 34.0f) ? 1.0f : 0.0f;
        float x2v = (x2f >= 0.0f && x2f < 34.0f) ? 1.0f : 0.0f;
        int x1 = (int)fminf(fmaxf(x1f, 0.0f), 33.0f);
        int x2 = (int)fminf(fmaxf(x2f, 0.0f), 33.0f);
        float dx = w - (float)x1;
        if (iw == 0) xbase = x1;
        float a = kw * (1.0f - dx) * x1v;
        float b = kw * dx * x2v;
        int i1 = x1 - xbase, i2 = x2 - xbase;
        Xw0 += (i1==0)?a:0.f; Xw1 += (i1==1)?a:0.f; Xw2 += (i1==2)?a:0.f; Xw3 += (i1==3)?a:0.f;
        Xw0 += (i2==0)?b:0.f; Xw1 += (i2==1)?b:0.f; Xw2 += (i2==2)?b:0.f; Xw3 += (i2==3)?b:0.f;
        cntx += kw;
    }
#pragma unroll
    for (int ih = 0; ih < 4; ++ih) {
        float h;
        {
#pragma clang fp contract(off)
            h = hstart + ((float)ih + 0.5f) * sub_h;
        }
        float kh  = (h > -1.0f && h < 34.0f) ? 1.0f : 0.0f;
        float y1f = floorf(h), y2f = ceilf(h);
        float y1v = (y1f >= 0.0f && y1f < 34.0f) ? 1.0f : 0.0f;
        float y2v = (y2f >= 0.0f && y2f < 34.0f) ? 1.0f : 0.0f;
        int y1 = (int)fminf(fmaxf(y1f, 0.0f), 33.0f);
        int y2 = (int)fminf(fmaxf(y2f, 0.0f), 33.0f);
        float dy = h - (float)y1;
        if (ih == 0) ybase = y1;
        float a = kh * (1.0f - dy) * y1v;
        float b = kh * dy * y2v;
        int i1 = y1 - ybase, i2 = y2 - ybase;
        Yw0 += (i1==0)?a:0.f; Yw1 += (i1==1)?a:0.f; Yw2 += (i1==2)?a:0.f; Yw3 += (i1==3)?a:0.f;
        Yw0 += (i2==0)?b:0.f; Yw1 += (i2==1)?b:0.f; Yw2 += (i2==2)?b:0.f; Yw3 += (i2==3)?b:0.f;
        cnty += kh;
    }
    float4 v0s = {0,0,0,0}, v1s = {0,0,0,0};
    float2 v2s = {0,0};
#pragma unroll
    for (int cy = 0; cy < 4; ++cy) {
        float wy = (cy==0)?Yw0:(cy==1)?Yw1:(cy==2)?Yw2:Yw3;
        if (wy != 0.0f) {
            int yy = min(ybase + cy, 33);
            const float* rowp = &tile[yy * (W * CPAD)];
#pragma unroll
            for (int cx = 0; cx < 4; ++cx) {
                float wx = (cx==0)?Xw0:(cx==1)?Xw1:(cx==2)?Xw2:Xw3;
                float wgt = wy * wx;
                if (wgt != 0.0f) {
                    int xx = min(xbase + cx, 33);
                    const float* t = rowp + xx * CPAD;
                    float4 a = *(const float4*)(t);
                    float4 b = *(const float4*)(t + 4);
                    float2 c2 = *(const float2*)(t + 8);
                    v0s.x += wgt*a.x; v0s.y += wgt*a.y; v0s.z += wgt*a.z; v0s.w += wgt*a.w;
                    v1s.x += wgt*b.x; v1s.y += wgt*b.y; v1s.z += wgt*b.z; v1s.w += wgt*b.w;
                    v2s.x += wgt*c2.x; v2s.y += wgt*c2.y;
                }
            }
        }
    }
    float cnt = cntx * cnty;
    if (!(cnt > 0.0f)) cnt = 1.0f;
    float inv = 1.0f / cnt;
    float r[10] = { v0s.x*inv, v0s.y*inv, v0s.z*inv, v0s.w*inv,
                    v1s.x*inv, v1s.y*inv, v1s.z*inv, v1s.w*inv,
                    v2s.x*inv, v2s.y*inv };
    float* __restrict__ o = dst + (size_t)n * R + p;
#pragma unroll
    for (int c = 0; c < C; ++c) o[c * P] = r[c];
}

extern "C" void kernel_launch(void* const* d_in, const int* in_sizes, int n_in,
                              void* d_out, int out_size, void* d_ws, size_t ws_size,
                              hipStream_t stream) {
    const float* ft   = (const float*)d_in[0];
    const float* rois = (const float*)d_in[1];
    float* out = (float*)d_out;
    const int N = in_sizes[1] / 5;

    const size_t packB = (size_t)P * SLAB_US * sizeof(ushort); // 1.81 MB
    const size_t wsOff = (packB + 255) & ~(size_t)255;
    const size_t need  = wsOff + (size_t)RU * N * sizeof(unsigned); // +16 MB
    if (d_ws != nullptr && ws_size >= need && (N % 64) == 0) {
        ushort*   ftB = (ushort*)d_ws;
        unsigned* ws2 = (unsigned*)((char*)d_ws + wsOff);
        dfmb_pack<<<dim3(P, (HW + 255) / 256), dim3(256), 0, stream>>>(ft, ftB);
        dfmb_main<<<dim3((N + 511) / 512, P), dim3(512), 0, stream>>>(ftB, rois, ws2, N);
        dfmb_phase2<<<dim3(N / 64), dim3(1024), 0, stream>>>(ws2, out, N);
    } else {
        dim3 grid1((N + 511) / 512, P);
        dfmb_phase1_direct<<<grid1, dim3(512), 0, stream>>>(ft, rois, out, N);
    }
}